// Round 2
// baseline (2368.803 us; speedup 1.0000x reference)
//
#include <hip/hip_runtime.h>
#include <hip/hip_bf16.h>
#include <stdint.h>

#define B_SZ 64
#define L_SZ 2048
#define V_SZ 1024
#define H_SZ 256
#define HALF_SZ 128
#define NTOK (B_SZ * L_SZ)   // 131072
#define CH 16384             // token chunk (8 chunks)

typedef unsigned short ushort_t;

__device__ __forceinline__ ushort_t f2bf(float f) {
    __hip_bfloat16 h = __float2bfloat16(f);
    return *reinterpret_cast<ushort_t*>(&h);
}

// ---------------------------------------------------------------------------
// Tiled f32 GEMM, 128x128 tile, BK=16, 256 threads, 8x8 micro-tile.
// Operates on a CHUNK of rows; seq is pre-offset to the chunk base.
// MODE 1: A = embed[seq[m]] (f32 gather), C = relu(acc + bias) -> bf16 (t1_c)
// MODE 2: A = bf16 (t1_c), C = acc + bias + embed[seq[m]][n] -> f32 (x_c)
// MODE 3: A = bf16 (h_c),  C = acc + bias -> f32 (proj + chunk offset)
// ---------------------------------------------------------------------------
template <int MODE, int K, int N>
__global__ __launch_bounds__(256) void gemm_k(
    const void* __restrict__ Ap, const float* __restrict__ Bp,
    const float* __restrict__ bias, void* __restrict__ Cp,
    const int* __restrict__ seq, const float* __restrict__ embed)
{
    __shared__ float As[16][128];
    __shared__ float Bs[16][128];

    const int tid = threadIdx.x;
    const int m0 = blockIdx.x * 128;   // chunk-local row base
    const int n0 = blockIdx.y * 128;

    const int smm = tid >> 1;           // 0..127 (A row within tile)
    const int skk = (tid & 1) * 8;      // 0 or 8 (A k sub-offset)
    const int bkk = tid >> 4;           // 0..15  (B k row)
    const int bnn = (tid & 15) * 8;     // 0..120 (B col offset)

    const float* arowf = (MODE == 1)
        ? (embed + (size_t)seq[m0 + smm] * H_SZ) : nullptr;
    const ushort_t* arowb = (MODE != 1)
        ? ((const ushort_t*)Ap + (size_t)(m0 + smm) * K) : nullptr;

    const int ty = tid >> 4;   // 0..15
    const int tx = tid & 15;   // 0..15

    float acc[8][8];
#pragma unroll
    for (int i = 0; i < 8; ++i)
#pragma unroll
        for (int j = 0; j < 8; ++j) acc[i][j] = 0.f;

    for (int kt = 0; kt < K / 16; ++kt) {
        const int k = kt * 16 + skk;
        if (MODE == 1) {
            float4 a0 = *(const float4*)(arowf + k);
            float4 a1 = *(const float4*)(arowf + k + 4);
            As[skk + 0][smm] = a0.x; As[skk + 1][smm] = a0.y;
            As[skk + 2][smm] = a0.z; As[skk + 3][smm] = a0.w;
            As[skk + 4][smm] = a1.x; As[skk + 5][smm] = a1.y;
            As[skk + 6][smm] = a1.z; As[skk + 7][smm] = a1.w;
        } else {
            uint4 av = *(const uint4*)(arowb + k);
            As[skk + 0][smm] = __uint_as_float(av.x << 16);
            As[skk + 1][smm] = __uint_as_float(av.x & 0xffff0000u);
            As[skk + 2][smm] = __uint_as_float(av.y << 16);
            As[skk + 3][smm] = __uint_as_float(av.y & 0xffff0000u);
            As[skk + 4][smm] = __uint_as_float(av.z << 16);
            As[skk + 5][smm] = __uint_as_float(av.z & 0xffff0000u);
            As[skk + 6][smm] = __uint_as_float(av.w << 16);
            As[skk + 7][smm] = __uint_as_float(av.w & 0xffff0000u);
        }
        {
            const float* bp = Bp + (size_t)(kt * 16 + bkk) * N + n0 + bnn;
            float4 b0 = *(const float4*)bp;
            float4 b1 = *(const float4*)(bp + 4);
            *(float4*)&Bs[bkk][bnn] = b0;
            *(float4*)&Bs[bkk][bnn + 4] = b1;
        }
        __syncthreads();
#pragma unroll
        for (int kk = 0; kk < 16; ++kk) {
            const float4 aL = *(const float4*)(&As[kk][ty * 8]);
            const float4 aH = *(const float4*)(&As[kk][ty * 8 + 4]);
            const float4 bL = *(const float4*)(&Bs[kk][tx * 8]);
            const float4 bH = *(const float4*)(&Bs[kk][tx * 8 + 4]);
            const float a[8] = {aL.x, aL.y, aL.z, aL.w, aH.x, aH.y, aH.z, aH.w};
            const float b[8] = {bL.x, bL.y, bL.z, bL.w, bH.x, bH.y, bH.z, bH.w};
#pragma unroll
            for (int i = 0; i < 8; ++i)
#pragma unroll
                for (int j = 0; j < 8; ++j)
                    acc[i][j] = fmaf(a[i], b[j], acc[i][j]);
        }
        __syncthreads();
    }

    // epilogue
    const int gn = n0 + tx * 8;
    float bl[8];
    {
        float4 c0 = *(const float4*)(bias + gn);
        float4 c1 = *(const float4*)(bias + gn + 4);
        bl[0] = c0.x; bl[1] = c0.y; bl[2] = c0.z; bl[3] = c0.w;
        bl[4] = c1.x; bl[5] = c1.y; bl[6] = c1.z; bl[7] = c1.w;
    }
#pragma unroll
    for (int i = 0; i < 8; ++i) {
        const int gm = m0 + ty * 8 + i;   // chunk-local row
        if (MODE == 1) {
            ushort_t ov[8];
#pragma unroll
            for (int j = 0; j < 8; ++j) {
                float vv = acc[i][j] + bl[j];
                vv = fmaxf(vv, 0.f);
                ov[j] = f2bf(vv);
            }
            uint4 pk;
            pk.x = (uint32_t)ov[0] | ((uint32_t)ov[1] << 16);
            pk.y = (uint32_t)ov[2] | ((uint32_t)ov[3] << 16);
            pk.z = (uint32_t)ov[4] | ((uint32_t)ov[5] << 16);
            pk.w = (uint32_t)ov[6] | ((uint32_t)ov[7] << 16);
            *(uint4*)((ushort_t*)Cp + (size_t)gm * N + gn) = pk;
        } else if (MODE == 2) {
            const float* er = embed + (size_t)seq[gm] * H_SZ + gn;
            float4 e0 = *(const float4*)er;
            float4 e1 = *(const float4*)(er + 4);
            float4 o0, o1;
            o0.x = acc[i][0] + bl[0] + e0.x;
            o0.y = acc[i][1] + bl[1] + e0.y;
            o0.z = acc[i][2] + bl[2] + e0.z;
            o0.w = acc[i][3] + bl[3] + e0.w;
            o1.x = acc[i][4] + bl[4] + e1.x;
            o1.y = acc[i][5] + bl[5] + e1.y;
            o1.z = acc[i][6] + bl[6] + e1.z;
            o1.w = acc[i][7] + bl[7] + e1.w;
            float* cr = (float*)Cp + (size_t)gm * N + gn;
            *(float4*)cr = o0;
            *(float4*)(cr + 4) = o1;
        } else {
            float4 o0, o1;
            o0.x = acc[i][0] + bl[0]; o0.y = acc[i][1] + bl[1];
            o0.z = acc[i][2] + bl[2]; o0.w = acc[i][3] + bl[3];
            o1.x = acc[i][4] + bl[4]; o1.y = acc[i][5] + bl[5];
            o1.z = acc[i][6] + bl[6]; o1.w = acc[i][7] + bl[7];
            float* cr = (float*)Cp + (size_t)gm * N + gn;
            *(float4*)cr = o0;
            *(float4*)(cr + 4) = o1;
        }
    }
}

// ---------------------------------------------------------------------------
// LayerNorm over H=256: one wave per token, 4 tokens per block (chunk-local).
// ---------------------------------------------------------------------------
__global__ __launch_bounds__(256) void ln_k(
    const float* __restrict__ x, const float* __restrict__ g,
    const float* __restrict__ bt, ushort_t* __restrict__ h)
{
    const int token = blockIdx.x * 4 + (threadIdx.x >> 6);
    const int lane = threadIdx.x & 63;
    const float* xr = x + (size_t)token * H_SZ + lane * 4;
    const float4 v = *(const float4*)xr;
    float s = v.x + v.y + v.z + v.w;
    float sq = v.x * v.x + v.y * v.y + v.z * v.z + v.w * v.w;
#pragma unroll
    for (int m = 1; m < 64; m <<= 1) {
        s += __shfl_xor(s, m);
        sq += __shfl_xor(sq, m);
    }
    const float mu = s * (1.f / H_SZ);
    const float var = sq * (1.f / H_SZ) - mu * mu;
    const float rs = rsqrtf(var + 1e-5f);
    const int idx = lane * 4;
    const float4 gg = *(const float4*)(g + idx);
    const float4 bb = *(const float4*)(bt + idx);
    ushort_t o0 = f2bf((v.x - mu) * rs * gg.x + bb.x);
    ushort_t o1 = f2bf((v.y - mu) * rs * gg.y + bb.y);
    ushort_t o2 = f2bf((v.z - mu) * rs * gg.z + bb.z);
    ushort_t o3 = f2bf((v.w - mu) * rs * gg.w + bb.w);
    uint2 pk;
    pk.x = (uint32_t)o0 | ((uint32_t)o1 << 16);
    pk.y = (uint32_t)o2 | ((uint32_t)o3 << 16);
    *(uint2*)(h + (size_t)token * H_SZ + idx) = pk;
}

// ---------------------------------------------------------------------------
// Per-token inverse norms over full proj (global tokens).
// invn[token][0] = 1/(||ks||^2+1e-6), [1] = e-half.
// ---------------------------------------------------------------------------
__global__ __launch_bounds__(256) void invn_k(
    const float* __restrict__ proj, float* __restrict__ invn)
{
    const int token = blockIdx.x * 4 + (threadIdx.x >> 6);
    const int lane = threadIdx.x & 63;
    const float4 v = *(const float4*)(proj + (size_t)token * H_SZ + lane * 4);
    float sq = v.x * v.x + v.y * v.y + v.z * v.z + v.w * v.w;
#pragma unroll
    for (int m = 1; m < 32; m <<= 1) sq += __shfl_xor(sq, m);
    if ((lane & 31) == 0)
        invn[(size_t)token * 2 + (lane >> 5)] = 1.0f / (sq + 1e-6f);
}

// ---------------------------------------------------------------------------
// Sequential scan. 512 blocks x 256 threads.
// block -> (pair = b*2+half, rowblock of 32 rows). Thread owns 16 cols of one
// row; dot combined across the 8 lanes of a row-group via shfl_xor.
// State M stays in VGPRs over all 2047 steps. k(t+1) prefetched.
// ---------------------------------------------------------------------------
__global__ __launch_bounds__(256) void scan_k(
    const float* __restrict__ proj, const float* __restrict__ invn,
    float* __restrict__ Mbuf)
{
    const int bid = blockIdx.x;       // 0..511
    const int pair = bid >> 2;        // 0..127  (= b*2 + half)
    const int rb = bid & 3;
    const int b = pair >> 1;
    const int half = pair & 1;
    const int tid = threadIdx.x;
    const int row = rb * 32 + (tid >> 3);  // 0..127
    const int cg = tid & 7;                // column group (16 floats)

    const float* kbase = proj + ((size_t)b * L_SZ) * H_SZ + half * HALF_SZ;
    const float* ibase = invn + ((size_t)b * L_SZ) * 2 + half;

    float M[16];
#pragma unroll
    for (int j = 0; j < 16; ++j) M[j] = 0.f;

    const float invL = 1.0f / (float)L_SZ;

    // preload t = 0
    float4 k0 = *(const float4*)(kbase + cg * 16);
    float4 k1 = *(const float4*)(kbase + cg * 16 + 4);
    float4 k2 = *(const float4*)(kbase + cg * 16 + 8);
    float4 k3 = *(const float4*)(kbase + cg * 16 + 12);
    float krow = kbase[row];
    float invc = ibase[0];

    for (int t = 0; t < L_SZ - 1; ++t) {
        // prefetch t+1 (t+1 <= 2047 is always a valid token)
        const float* kn = kbase + (size_t)(t + 1) * H_SZ;
        const float4 n0v = *(const float4*)(kn + cg * 16);
        const float4 n1v = *(const float4*)(kn + cg * 16 + 4);
        const float4 n2v = *(const float4*)(kn + cg * 16 + 8);
        const float4 n3v = *(const float4*)(kn + cg * 16 + 12);
        const float krn = kn[row];
        const float invnx = ibase[(size_t)(t + 1) * 2];

        float p = M[0] * k0.x + M[1] * k0.y + M[2] * k0.z + M[3] * k0.w
                + M[4] * k1.x + M[5] * k1.y + M[6] * k1.z + M[7] * k1.w
                + M[8] * k2.x + M[9] * k2.y + M[10] * k2.z + M[11] * k2.w
                + M[12] * k3.x + M[13] * k3.y + M[14] * k3.z + M[15] * k3.w;
        p += __shfl_xor(p, 1);
        p += __shfl_xor(p, 2);
        p += __shfl_xor(p, 4);

        const float dv = krow - p * invc;
        const float coef = half ? dv * ((float)(t + 1) * invL) : dv;

        M[0]  = fmaf(coef, k0.x, M[0]);
        M[1]  = fmaf(coef, k0.y, M[1]);
        M[2]  = fmaf(coef, k0.z, M[2]);
        M[3]  = fmaf(coef, k0.w, M[3]);
        M[4]  = fmaf(coef, k1.x, M[4]);
        M[5]  = fmaf(coef, k1.y, M[5]);
        M[6]  = fmaf(coef, k1.z, M[6]);
        M[7]  = fmaf(coef, k1.w, M[7]);
        M[8]  = fmaf(coef, k2.x, M[8]);
        M[9]  = fmaf(coef, k2.y, M[9]);
        M[10] = fmaf(coef, k2.z, M[10]);
        M[11] = fmaf(coef, k2.w, M[11]);
        M[12] = fmaf(coef, k3.x, M[12]);
        M[13] = fmaf(coef, k3.y, M[13]);
        M[14] = fmaf(coef, k3.z, M[14]);
        M[15] = fmaf(coef, k3.w, M[15]);

        k0 = n0v; k1 = n1v; k2 = n2v; k3 = n3v;
        krow = krn; invc = invnx;
    }

    float* op = Mbuf + ((size_t)pair * 128 + row) * 128 + cg * 16;
    *(float4*)(op + 0)  = make_float4(M[0], M[1], M[2], M[3]);
    *(float4*)(op + 4)  = make_float4(M[4], M[5], M[6], M[7]);
    *(float4*)(op + 8)  = make_float4(M[8], M[9], M[10], M[11]);
    *(float4*)(op + 12) = make_float4(M[12], M[13], M[14], M[15]);
}

// ---------------------------------------------------------------------------
// c[b, half*128 + i] = dot(M[pair][i][:], q_half)   (q = proj at token L-1)
// ---------------------------------------------------------------------------
__global__ __launch_bounds__(128) void c_k(
    const float* __restrict__ Mbuf, const float* __restrict__ proj,
    float* __restrict__ c)
{
    const int pair = blockIdx.x;     // 0..127
    const int i = threadIdx.x;       // 0..127
    const int b = pair >> 1;
    const int half = pair & 1;
    const float* q = proj + ((size_t)b * L_SZ + (L_SZ - 1)) * H_SZ + half * HALF_SZ;
    const float* Mr = Mbuf + ((size_t)pair * 128 + i) * 128;
    float acc = 0.f;
#pragma unroll 8
    for (int j = 0; j < 128; j += 4) {
        const float4 m4 = *(const float4*)(Mr + j);
        const float4 q4 = *(const float4*)(q + j);
        acc += m4.x * q4.x + m4.y * q4.y + m4.z * q4.z + m4.w * q4.w;
    }
    c[b * H_SZ + half * HALF_SZ + i] = acc;
}

// ---------------------------------------------------------------------------
// out[b, v] = sum_h c[b,h] * out_w[h,v] + out_b[v]   (f32 store)
// ---------------------------------------------------------------------------
__global__ __launch_bounds__(256) void out_k(
    const float* __restrict__ c, const float* __restrict__ w,
    const float* __restrict__ ob, float* __restrict__ out)
{
    const int b = blockIdx.x >> 2;
    const int v = ((blockIdx.x & 3) << 8) + threadIdx.x;
    const float* cb = c + b * H_SZ;
    float acc = ob[v];
#pragma unroll 4
    for (int hh = 0; hh < H_SZ; ++hh)
        acc = fmaf(cb[hh], w[(size_t)hh * V_SZ + v], acc);
    out[(size_t)b * V_SZ + v] = acc;
}

// ---------------------------------------------------------------------------
extern "C" void kernel_launch(void* const* d_in, const int* in_sizes, int n_in,
                              void* d_out, int out_size, void* d_ws, size_t ws_size,
                              hipStream_t stream)
{
    const int*   seq   = (const int*)d_in[0];
    const float* embed = (const float*)d_in[1];
    const float* w1    = (const float*)d_in[2];
    const float* b1    = (const float*)d_in[3];
    const float* w2    = (const float*)d_in[4];
    const float* b2    = (const float*)d_in[5];
    const float* ln_g  = (const float*)d_in[6];
    const float* ln_b  = (const float*)d_in[7];
    const float* kp_w  = (const float*)d_in[8];
    const float* kp_b  = (const float*)d_in[9];
    const float* out_w = (const float*)d_in[10];
    const float* out_b = (const float*)d_in[11];

    char* ws = (char*)d_ws;
    size_t off = 0;
    auto alloc = [&](size_t bytes) -> void* {
        void* p = ws + off;
        off += (bytes + 255) & ~(size_t)255;
        return p;
    };

    // Persistent across chunks:
    float*    proj = (float*)alloc((size_t)NTOK * H_SZ * sizeof(float));   // 128 MB
    // Chunk-sized temporaries (reused each chunk):
    ushort_t* t1_c = (ushort_t*)alloc((size_t)CH * 512 * sizeof(ushort_t)); // 16 MB
    float*    x_c  = (float*)alloc((size_t)CH * H_SZ * sizeof(float));      // 16 MB
    ushort_t* h_c  = (ushort_t*)alloc((size_t)CH * H_SZ * sizeof(ushort_t)); // 8 MB
    // Scan outputs:
    float*    invn = (float*)alloc((size_t)NTOK * 2 * sizeof(float));       // 1 MB
    float*    Mbuf = (float*)alloc((size_t)128 * 128 * 128 * sizeof(float)); // 8 MB
    float*    cbuf = (float*)alloc((size_t)B_SZ * H_SZ * sizeof(float));
    float*    outp = (float*)d_out;
    // total ws use ~= 177 MB

    const dim3 blk(256);

    for (int c = 0; c < NTOK / CH; ++c) {
        const int base = c * CH;
        const int* seq_c = seq + base;
        // GEMM1: t1_c = relu(embed[seq] @ w1 + b1)     M=CH K=256 N=512
        gemm_k<1, 256, 512><<<dim3(CH / 128, 4), blk, 0, stream>>>(
            nullptr, w1, b1, t1_c, seq_c, embed);
        // GEMM2: x_c = t1_c @ w2 + b2 + embed[seq]     M=CH K=512 N=256
        gemm_k<2, 512, 256><<<dim3(CH / 128, 2), blk, 0, stream>>>(
            t1_c, w2, b2, x_c, seq_c, embed);
        // LN: h_c = LN(x_c) * g + b  (bf16)
        ln_k<<<dim3(CH / 4), blk, 0, stream>>>(x_c, ln_g, ln_b, h_c);
        // GEMM3: proj[base..] = h_c @ kp_w + kp_b      M=CH K=256 N=256
        gemm_k<3, 256, 256><<<dim3(CH / 128, 2), blk, 0, stream>>>(
            h_c, kp_w, kp_b, proj + (size_t)base * H_SZ, seq_c, embed);
    }

    // inverse squared norms of both halves per token
    invn_k<<<dim3(NTOK / 4), blk, 0, stream>>>(proj, invn);
    // sequential delta-rule scan -> final M matrices
    scan_k<<<dim3(512), blk, 0, stream>>>(proj, invn, Mbuf);
    // c = M q
    c_k<<<dim3(128), dim3(128), 0, stream>>>(Mbuf, proj, cbuf);
    // out = c @ out_w + out_b  (f32)
    out_k<<<dim3(B_SZ * 4), blk, 0, stream>>>(cbuf, out_w, out_b, outp);
}

// Round 3
// 1081.298 us; speedup vs baseline: 2.1907x; 2.1907x over previous
//
#include <hip/hip_runtime.h>
#include <hip/hip_bf16.h>
#include <stdint.h>

#define B_SZ 64
#define L_SZ 2048
#define V_SZ 1024
#define H_SZ 256
#define HALF_SZ 128
#define NTOK (B_SZ * L_SZ)   // 131072
#define CH 16384             // token chunk (8 chunks)

typedef unsigned short ushort_t;
typedef __attribute__((ext_vector_type(8))) short bf16x8;
typedef __attribute__((ext_vector_type(4))) float f32x4;

__device__ __forceinline__ ushort_t f2bf(float f) {
    __hip_bfloat16 h = __float2bfloat16(f);
    return *reinterpret_cast<ushort_t*>(&h);
}

// ---------------------------------------------------------------------------
// f32 -> bf16 convert (same layout). n multiple of 1024.
// ---------------------------------------------------------------------------
__global__ __launch_bounds__(256) void cvt_bf16_k(
    const float* __restrict__ src, ushort_t* __restrict__ dst, int n)
{
    int i = (blockIdx.x * 256 + threadIdx.x) * 4;
    if (i >= n) return;
    float4 v = *(const float4*)(src + i);
    uint2 pk;
    pk.x = (uint32_t)f2bf(v.x) | ((uint32_t)f2bf(v.y) << 16);
    pk.y = (uint32_t)f2bf(v.z) | ((uint32_t)f2bf(v.w) << 16);
    *(uint2*)(dst + i) = pk;
}

// ---------------------------------------------------------------------------
// dst[n*K + k] = bf16(src[k*N + n])  — weight transpose + convert (tiny).
// ---------------------------------------------------------------------------
__global__ __launch_bounds__(256) void transpose_cvt_k(
    const float* __restrict__ src, ushort_t* __restrict__ dst, int K, int N)
{
    int idx = blockIdx.x * 256 + threadIdx.x;
    if (idx >= K * N) return;
    int n = idx / K;
    int k = idx - n * K;
    dst[idx] = f2bf(src[(size_t)k * N + n]);
}

// ---------------------------------------------------------------------------
// bf16 MFMA GEMM: C[128 x 128-tile] = A[M][K] @ BT[N][K]^T, 256 thr / 4 waves.
// BK=64, LDS XOR-swizzled (chunk ^= row&7) for conflict-free ds_read_b128.
// MODE 1: A row = embed_bf[seq[m]]; C = relu(acc+bias) -> bf16
// MODE 2: A = t1 bf16;  C = acc + bias + embed_f32[seq[m]][n] -> f32
// MODE 3: A = h bf16;   C = acc + bias -> f32
// ---------------------------------------------------------------------------
template <int MODE, int K, int N>
__global__ __launch_bounds__(256) void gemm_mfma(
    const ushort_t* __restrict__ A, const ushort_t* __restrict__ BT,
    const float* __restrict__ bias, void* __restrict__ Cp,
    const int* __restrict__ seq, const float* __restrict__ embed)
{
    __shared__ __align__(16) ushort_t Asm[128 * 64];
    __shared__ __align__(16) ushort_t Bsm[128 * 64];

    const int tid = threadIdx.x;
    const int m0 = blockIdx.x * 128;
    const int n0 = blockIdx.y * 128;
    const int w = tid >> 6;
    const int l = tid & 63;
    const int wr = w >> 1;   // wave tile row (0..1)
    const int wc = w & 1;    // wave tile col (0..1)

    // staging row base pointers (rows fixed across K-loop)
    const ushort_t* arow[4];
    const ushort_t* brow[4];
#pragma unroll
    for (int i = 0; i < 4; ++i) {
        const int flat = i * 256 + tid;       // 0..1023
        const int r = flat >> 3;              // 0..127
        const int gr = (MODE == 1) ? seq[m0 + r] : (m0 + r);
        arow[i] = A + (size_t)gr * K;
        brow[i] = BT + (size_t)(n0 + r) * K;
    }

    f32x4 acc[4][4];
#pragma unroll
    for (int mi = 0; mi < 4; ++mi)
#pragma unroll
        for (int nj = 0; nj < 4; ++nj)
            acc[mi][nj] = (f32x4){0.f, 0.f, 0.f, 0.f};

    for (int kt = 0; kt < K / 64; ++kt) {
#pragma unroll
        for (int i = 0; i < 4; ++i) {
            const int flat = i * 256 + tid;
            const int r = flat >> 3;          // tile row
            const int c = flat & 7;           // 16B chunk within 128B row
            const int cs = c ^ (r & 7);       // swizzled chunk
            uint4 av = *(const uint4*)(arow[i] + kt * 64 + c * 8);
            *(uint4*)&Asm[r * 64 + cs * 8] = av;
            uint4 bv = *(const uint4*)(brow[i] + kt * 64 + c * 8);
            *(uint4*)&Bsm[r * 64 + cs * 8] = bv;
        }
        __syncthreads();
#pragma unroll
        for (int kh = 0; kh < 2; ++kh) {
            bf16x8 af[4], bfr[4];
#pragma unroll
            for (int mi = 0; mi < 4; ++mi) {
                const int r = wr * 64 + mi * 16 + (l & 15);
                const int c = (kh * 4 + (l >> 4)) ^ (r & 7);
                af[mi] = *(const bf16x8*)&Asm[r * 64 + c * 8];
            }
#pragma unroll
            for (int nj = 0; nj < 4; ++nj) {
                const int r = wc * 64 + nj * 16 + (l & 15);
                const int c = (kh * 4 + (l >> 4)) ^ (r & 7);
                bfr[nj] = *(const bf16x8*)&Bsm[r * 64 + c * 8];
            }
#pragma unroll
            for (int mi = 0; mi < 4; ++mi)
#pragma unroll
                for (int nj = 0; nj < 4; ++nj)
                    acc[mi][nj] = __builtin_amdgcn_mfma_f32_16x16x32_bf16(
                        af[mi], bfr[nj], acc[mi][nj], 0, 0, 0);
        }
        __syncthreads();
    }

    // epilogue: C/D layout col = lane&15, row = (lane>>4)*4 + reg
    const int cl = l & 15;
    const int rg = l >> 4;
    float bv[4];
#pragma unroll
    for (int nj = 0; nj < 4; ++nj)
        bv[nj] = bias[n0 + wc * 64 + nj * 16 + cl];

#pragma unroll
    for (int mi = 0; mi < 4; ++mi) {
#pragma unroll
        for (int i = 0; i < 4; ++i) {
            const int row = m0 + wr * 64 + mi * 16 + rg * 4 + i;  // chunk-local
            const float* erow = (MODE == 2)
                ? (embed + (size_t)seq[row] * H_SZ) : nullptr;
#pragma unroll
            for (int nj = 0; nj < 4; ++nj) {
                const int gn = n0 + wc * 64 + nj * 16 + cl;
                float v = acc[mi][nj][i] + bv[nj];
                if (MODE == 1) {
                    v = fmaxf(v, 0.f);
                    ((ushort_t*)Cp)[(size_t)row * N + gn] = f2bf(v);
                } else if (MODE == 2) {
                    ((float*)Cp)[(size_t)row * N + gn] = v + erow[gn];
                } else {
                    ((float*)Cp)[(size_t)row * N + gn] = v;
                }
            }
        }
    }
}

// ---------------------------------------------------------------------------
// LayerNorm over H=256: one wave per token, 4 tokens per block (chunk-local).
// ---------------------------------------------------------------------------
__global__ __launch_bounds__(256) void ln_k(
    const float* __restrict__ x, const float* __restrict__ g,
    const float* __restrict__ bt, ushort_t* __restrict__ h)
{
    const int token = blockIdx.x * 4 + (threadIdx.x >> 6);
    const int lane = threadIdx.x & 63;
    const float* xr = x + (size_t)token * H_SZ + lane * 4;
    const float4 v = *(const float4*)xr;
    float s = v.x + v.y + v.z + v.w;
    float sq = v.x * v.x + v.y * v.y + v.z * v.z + v.w * v.w;
#pragma unroll
    for (int m = 1; m < 64; m <<= 1) {
        s += __shfl_xor(s, m);
        sq += __shfl_xor(sq, m);
    }
    const float mu = s * (1.f / H_SZ);
    const float var = sq * (1.f / H_SZ) - mu * mu;
    const float rs = rsqrtf(var + 1e-5f);
    const int idx = lane * 4;
    const float4 gg = *(const float4*)(g + idx);
    const float4 bb = *(const float4*)(bt + idx);
    ushort_t o0 = f2bf((v.x - mu) * rs * gg.x + bb.x);
    ushort_t o1 = f2bf((v.y - mu) * rs * gg.y + bb.y);
    ushort_t o2 = f2bf((v.z - mu) * rs * gg.z + bb.z);
    ushort_t o3 = f2bf((v.w - mu) * rs * gg.w + bb.w);
    uint2 pk;
    pk.x = (uint32_t)o0 | ((uint32_t)o1 << 16);
    pk.y = (uint32_t)o2 | ((uint32_t)o3 << 16);
    *(uint2*)(h + (size_t)token * H_SZ + idx) = pk;
}

// ---------------------------------------------------------------------------
// Per-token inverse squared norms of both proj halves.
// ---------------------------------------------------------------------------
__global__ __launch_bounds__(256) void invn_k(
    const float* __restrict__ proj, float* __restrict__ invn)
{
    const int token = blockIdx.x * 4 + (threadIdx.x >> 6);
    const int lane = threadIdx.x & 63;
    const float4 v = *(const float4*)(proj + (size_t)token * H_SZ + lane * 4);
    float sq = v.x * v.x + v.y * v.y + v.z * v.z + v.w * v.w;
#pragma unroll
    for (int m = 1; m < 32; m <<= 1) sq += __shfl_xor(sq, m);
    if ((lane & 31) == 0)
        invn[(size_t)token * 2 + (lane >> 5)] = 1.0f / (sq + 1e-6f);
}

// ---------------------------------------------------------------------------
// Sequential scan v2: 1024 blocks x 256 threads.
// block -> (pair = bid>>3, 16 rows). Thread: row = rb*16 + (tid>>4), owns 8
// cols (cg = tid&15). Dot reduced over 16 lanes via 4 shfl_xor.
// 4-step register prefetch pipeline hides HBM latency.
// ---------------------------------------------------------------------------
__global__ __launch_bounds__(256) void scan_k(
    const float* __restrict__ proj, const float* __restrict__ invn,
    float* __restrict__ Mbuf)
{
    const int bid = blockIdx.x;         // 0..1023
    const int pair = bid >> 3;          // 0..127 (= b*2 + half)
    const int rb = bid & 7;
    const int b = pair >> 1;
    const int half = pair & 1;
    const int tid = threadIdx.x;
    const int row = rb * 16 + (tid >> 4);   // 0..127
    const int cg = tid & 15;                // 8 cols each

    const float* kbase = proj + (size_t)b * L_SZ * H_SZ + half * HALF_SZ;
    const float* ibase = invn + (size_t)b * L_SZ * 2 + half;

    float M[8];
#pragma unroll
    for (int j = 0; j < 8; ++j) M[j] = 0.f;

    float4 ka[4], kb[4];
    float kr[4], iv[4];
#pragma unroll
    for (int s = 0; s < 4; ++s) {
        const float* kp = kbase + (size_t)s * H_SZ;
        ka[s] = *(const float4*)(kp + cg * 8);
        kb[s] = *(const float4*)(kp + cg * 8 + 4);
        kr[s] = kp[row];
        iv[s] = ibase[(size_t)s * 2];
    }

    const float invL = 1.0f / (float)L_SZ;

#define SCAN_STEP(S, T, PF)                                                  \
    {                                                                        \
        float4 na, nb; float nk = 0.f, ni = 0.f;                             \
        if (PF) {                                                            \
            const float* kp = kbase + (size_t)((T) + 4) * H_SZ;              \
            na = *(const float4*)(kp + cg * 8);                              \
            nb = *(const float4*)(kp + cg * 8 + 4);                          \
            nk = kp[row];                                                    \
            ni = ibase[(size_t)((T) + 4) * 2];                               \
        }                                                                    \
        float p0 = M[0] * ka[S].x + M[1] * ka[S].y                           \
                 + M[2] * ka[S].z + M[3] * ka[S].w;                          \
        float p1 = M[4] * kb[S].x + M[5] * kb[S].y                           \
                 + M[6] * kb[S].z + M[7] * kb[S].w;                          \
        float p = p0 + p1;                                                   \
        p += __shfl_xor(p, 1);                                               \
        p += __shfl_xor(p, 2);                                               \
        p += __shfl_xor(p, 4);                                               \
        p += __shfl_xor(p, 8);                                               \
        const float dv = kr[S] - p * iv[S];                                  \
        const float coef = half ? dv * ((float)((T) + 1) * invL) : dv;       \
        M[0] = fmaf(coef, ka[S].x, M[0]);                                    \
        M[1] = fmaf(coef, ka[S].y, M[1]);                                    \
        M[2] = fmaf(coef, ka[S].z, M[2]);                                    \
        M[3] = fmaf(coef, ka[S].w, M[3]);                                    \
        M[4] = fmaf(coef, kb[S].x, M[4]);                                    \
        M[5] = fmaf(coef, kb[S].y, M[5]);                                    \
        M[6] = fmaf(coef, kb[S].z, M[6]);                                    \
        M[7] = fmaf(coef, kb[S].w, M[7]);                                    \
        if (PF) { ka[S] = na; kb[S] = nb; kr[S] = nk; iv[S] = ni; }          \
    }

    // main: 511 quads = steps 0..2043 (prefetch reaches token 2047, valid)
    for (int q = 0; q < 511; ++q) {
        const int t = q * 4;
        SCAN_STEP(0, t + 0, 1)
        SCAN_STEP(1, t + 1, 1)
        SCAN_STEP(2, t + 2, 1)
        SCAN_STEP(3, t + 3, 1)
    }
    // tail: steps 2044..2046 from slots 0..2
    SCAN_STEP(0, 2044, 0)
    SCAN_STEP(1, 2045, 0)
    SCAN_STEP(2, 2046, 0)
#undef SCAN_STEP

    float* op = Mbuf + ((size_t)pair * 128 + row) * 128 + cg * 8;
    *(float4*)(op + 0) = make_float4(M[0], M[1], M[2], M[3]);
    *(float4*)(op + 4) = make_float4(M[4], M[5], M[6], M[7]);
}

// ---------------------------------------------------------------------------
// c[b, half*128 + i] = dot(M[pair][i][:], q_half)
// ---------------------------------------------------------------------------
__global__ __launch_bounds__(128) void c_k(
    const float* __restrict__ Mbuf, const float* __restrict__ proj,
    float* __restrict__ c)
{
    const int pair = blockIdx.x;
    const int i = threadIdx.x;
    const int b = pair >> 1;
    const int half = pair & 1;
    const float* q = proj + ((size_t)b * L_SZ + (L_SZ - 1)) * H_SZ + half * HALF_SZ;
    const float* Mr = Mbuf + ((size_t)pair * 128 + i) * 128;
    float acc = 0.f;
#pragma unroll 8
    for (int j = 0; j < 128; j += 4) {
        const float4 m4 = *(const float4*)(Mr + j);
        const float4 q4 = *(const float4*)(q + j);
        acc += m4.x * q4.x + m4.y * q4.y + m4.z * q4.z + m4.w * q4.w;
    }
    c[b * H_SZ + half * HALF_SZ + i] = acc;
}

// ---------------------------------------------------------------------------
// out[b, v] = sum_h c[b,h] * out_w[h,v] + out_b[v]   (f32 store)
// ---------------------------------------------------------------------------
__global__ __launch_bounds__(256) void out_k(
    const float* __restrict__ c, const float* __restrict__ w,
    const float* __restrict__ ob, float* __restrict__ out)
{
    const int b = blockIdx.x >> 2;
    const int v = ((blockIdx.x & 3) << 8) + threadIdx.x;
    const float* cb = c + b * H_SZ;
    float acc = ob[v];
#pragma unroll 4
    for (int hh = 0; hh < H_SZ; ++hh)
        acc = fmaf(cb[hh], w[(size_t)hh * V_SZ + v], acc);
    out[(size_t)b * V_SZ + v] = acc;
}

// ---------------------------------------------------------------------------
extern "C" void kernel_launch(void* const* d_in, const int* in_sizes, int n_in,
                              void* d_out, int out_size, void* d_ws, size_t ws_size,
                              hipStream_t stream)
{
    const int*   seq   = (const int*)d_in[0];
    const float* embed = (const float*)d_in[1];
    const float* w1    = (const float*)d_in[2];
    const float* b1    = (const float*)d_in[3];
    const float* w2    = (const float*)d_in[4];
    const float* b2    = (const float*)d_in[5];
    const float* ln_g  = (const float*)d_in[6];
    const float* ln_b  = (const float*)d_in[7];
    const float* kp_w  = (const float*)d_in[8];
    const float* kp_b  = (const float*)d_in[9];
    const float* out_w = (const float*)d_in[10];
    const float* out_b = (const float*)d_in[11];

    char* ws = (char*)d_ws;
    size_t off = 0;
    auto alloc = [&](size_t bytes) -> void* {
        void* p = ws + off;
        off += (bytes + 255) & ~(size_t)255;
        return p;
    };

    float*    proj = (float*)alloc((size_t)NTOK * H_SZ * sizeof(float));     // 128 MB
    ushort_t* t1_c = (ushort_t*)alloc((size_t)CH * 512 * sizeof(ushort_t));  // 16 MB
    float*    x_c  = (float*)alloc((size_t)CH * H_SZ * sizeof(float));       // 16 MB
    ushort_t* h_c  = (ushort_t*)alloc((size_t)CH * H_SZ * sizeof(ushort_t)); // 8 MB
    float*    invn = (float*)alloc((size_t)NTOK * 2 * sizeof(float));        // 1 MB
    float*    Mbuf = (float*)alloc((size_t)128 * 128 * 128 * sizeof(float)); // 8 MB
    float*    cbuf = (float*)alloc((size_t)B_SZ * H_SZ * sizeof(float));
    // bf16 weight copies
    ushort_t* embed_bf = (ushort_t*)alloc((size_t)V_SZ * H_SZ * 2);          // 512 KB
    ushort_t* w1T = (ushort_t*)alloc((size_t)512 * 256 * 2);                 // 256 KB
    ushort_t* w2T = (ushort_t*)alloc((size_t)256 * 512 * 2);                 // 256 KB
    ushort_t* kpT = (ushort_t*)alloc((size_t)256 * 256 * 2);                 // 128 KB
    float*    outp = (float*)d_out;

    const dim3 blk(256);

    // weight preconversion (bf16 / transposed-bf16)
    cvt_bf16_k<<<dim3((V_SZ * H_SZ) / 1024), blk, 0, stream>>>(
        embed, embed_bf, V_SZ * H_SZ);
    transpose_cvt_k<<<dim3((256 * 512) / 256), blk, 0, stream>>>(w1, w1T, 256, 512);
    transpose_cvt_k<<<dim3((512 * 256) / 256), blk, 0, stream>>>(w2, w2T, 512, 256);
    transpose_cvt_k<<<dim3((256 * 256) / 256), blk, 0, stream>>>(kp_w, kpT, 256, 256);

    for (int c = 0; c < NTOK / CH; ++c) {
        const int base = c * CH;
        const int* seq_c = seq + base;
        // GEMM1: t1 = relu(embed[seq] @ w1 + b1)     M=CH K=256 N=512
        gemm_mfma<1, 256, 512><<<dim3(CH / 128, 4), blk, 0, stream>>>(
            embed_bf, w1T, b1, t1_c, seq_c, nullptr);
        // GEMM2: x = t1 @ w2 + b2 + embed[seq]       M=CH K=512 N=256
        gemm_mfma<2, 512, 256><<<dim3(CH / 128, 2), blk, 0, stream>>>(
            t1_c, w2T, b2, x_c, seq_c, embed);
        // LN: h = LN(x) * g + b  (bf16)
        ln_k<<<dim3(CH / 4), blk, 0, stream>>>(x_c, ln_g, ln_b, h_c);
        // GEMM3: proj = h @ kp_w + kp_b              M=CH K=256 N=256
        gemm_mfma<3, 256, 256><<<dim3(CH / 128, 2), blk, 0, stream>>>(
            h_c, kpT, kp_b, proj + (size_t)base * H_SZ, seq_c, nullptr);
    }

    invn_k<<<dim3(NTOK / 4), blk, 0, stream>>>(proj, invn);
    scan_k<<<dim3(1024), blk, 0, stream>>>(proj, invn, Mbuf);
    c_k<<<dim3(128), dim3(128), 0, stream>>>(Mbuf, proj, cbuf);
    out_k<<<dim3(B_SZ * 4), blk, 0, stream>>>(cbuf, out_w, out_b, outp);
}

// Round 5
// 799.646 us; speedup vs baseline: 2.9623x; 1.3522x over previous
//
#include <hip/hip_runtime.h>
#include <hip/hip_bf16.h>
#include <stdint.h>

#define B_SZ 64
#define L_SZ 2048
#define V_SZ 1024
#define H_SZ 256
#define HALF_SZ 128
#define NTOK (B_SZ * L_SZ)   // 131072
#define CH 16384             // token chunk (8 chunks)

typedef unsigned short ushort_t;
typedef __attribute__((ext_vector_type(8))) short bf16x8;
typedef __attribute__((ext_vector_type(4))) float f32x4;

__device__ __forceinline__ ushort_t f2bf(float f) {
    __hip_bfloat16 h = __float2bfloat16(f);
    return *reinterpret_cast<ushort_t*>(&h);
}

// ---------------------------------------------------------------------------
// f32 -> bf16 convert (same layout). n multiple of 1024.
// ---------------------------------------------------------------------------
__global__ __launch_bounds__(256) void cvt_bf16_k(
    const float* __restrict__ src, ushort_t* __restrict__ dst, int n)
{
    int i = (blockIdx.x * 256 + threadIdx.x) * 4;
    if (i >= n) return;
    float4 v = *(const float4*)(src + i);
    uint2 pk;
    pk.x = (uint32_t)f2bf(v.x) | ((uint32_t)f2bf(v.y) << 16);
    pk.y = (uint32_t)f2bf(v.z) | ((uint32_t)f2bf(v.w) << 16);
    *(uint2*)(dst + i) = pk;
}

// ---------------------------------------------------------------------------
// dst[n*K + k] = bf16(src[k*N + n])  — weight transpose + convert (tiny).
// ---------------------------------------------------------------------------
__global__ __launch_bounds__(256) void transpose_cvt_k(
    const float* __restrict__ src, ushort_t* __restrict__ dst, int K, int N)
{
    int idx = blockIdx.x * 256 + threadIdx.x;
    if (idx >= K * N) return;
    int n = idx / K;
    int k = idx - n * K;
    dst[idx] = f2bf(src[(size_t)k * N + n]);
}

// ---------------------------------------------------------------------------
// bf16 MFMA GEMM: C[128 x 128-tile] = A[M][K] @ BT[N][K]^T, 256 thr / 4 waves.
// BK=64, LDS XOR-swizzled (chunk ^= row&7) for conflict-free ds_read_b128.
// MODE 1: A row = embed_bf[seq[m]]; C = relu(acc+bias) -> bf16
// MODE 2: A = t1 bf16;  C = acc + bias + embed_f32[seq[m]][n] -> f32
// MODE 3: A = h bf16;   C = acc + bias -> f32
// ---------------------------------------------------------------------------
template <int MODE, int K, int N>
__global__ __launch_bounds__(256) void gemm_mfma(
    const ushort_t* __restrict__ A, const ushort_t* __restrict__ BT,
    const float* __restrict__ bias, void* __restrict__ Cp,
    const int* __restrict__ seq, const float* __restrict__ embed)
{
    __shared__ __align__(16) ushort_t Asm[128 * 64];
    __shared__ __align__(16) ushort_t Bsm[128 * 64];

    const int tid = threadIdx.x;
    const int m0 = blockIdx.x * 128;
    const int n0 = blockIdx.y * 128;
    const int w = tid >> 6;
    const int l = tid & 63;
    const int wr = w >> 1;   // wave tile row (0..1)
    const int wc = w & 1;    // wave tile col (0..1)

    // staging row base pointers (rows fixed across K-loop)
    const ushort_t* arow[4];
    const ushort_t* brow[4];
#pragma unroll
    for (int i = 0; i < 4; ++i) {
        const int flat = i * 256 + tid;       // 0..1023
        const int r = flat >> 3;              // 0..127
        const int gr = (MODE == 1) ? seq[m0 + r] : (m0 + r);
        arow[i] = A + (size_t)gr * K;
        brow[i] = BT + (size_t)(n0 + r) * K;
    }

    f32x4 acc[4][4];
#pragma unroll
    for (int mi = 0; mi < 4; ++mi)
#pragma unroll
        for (int nj = 0; nj < 4; ++nj)
            acc[mi][nj] = (f32x4){0.f, 0.f, 0.f, 0.f};

    for (int kt = 0; kt < K / 64; ++kt) {
#pragma unroll
        for (int i = 0; i < 4; ++i) {
            const int flat = i * 256 + tid;
            const int r = flat >> 3;          // tile row
            const int c = flat & 7;           // 16B chunk within 128B row
            const int cs = c ^ (r & 7);       // swizzled chunk
            uint4 av = *(const uint4*)(arow[i] + kt * 64 + c * 8);
            *(uint4*)&Asm[r * 64 + cs * 8] = av;
            uint4 bv = *(const uint4*)(brow[i] + kt * 64 + c * 8);
            *(uint4*)&Bsm[r * 64 + cs * 8] = bv;
        }
        __syncthreads();
#pragma unroll
        for (int kh = 0; kh < 2; ++kh) {
            bf16x8 af[4], bfr[4];
#pragma unroll
            for (int mi = 0; mi < 4; ++mi) {
                const int r = wr * 64 + mi * 16 + (l & 15);
                const int c = (kh * 4 + (l >> 4)) ^ (r & 7);
                af[mi] = *(const bf16x8*)&Asm[r * 64 + c * 8];
            }
#pragma unroll
            for (int nj = 0; nj < 4; ++nj) {
                const int r = wc * 64 + nj * 16 + (l & 15);
                const int c = (kh * 4 + (l >> 4)) ^ (r & 7);
                bfr[nj] = *(const bf16x8*)&Bsm[r * 64 + c * 8];
            }
#pragma unroll
            for (int mi = 0; mi < 4; ++mi)
#pragma unroll
                for (int nj = 0; nj < 4; ++nj)
                    acc[mi][nj] = __builtin_amdgcn_mfma_f32_16x16x32_bf16(
                        af[mi], bfr[nj], acc[mi][nj], 0, 0, 0);
        }
        __syncthreads();
    }

    // epilogue: C/D layout col = lane&15, row = (lane>>4)*4 + reg
    const int cl = l & 15;
    const int rg = l >> 4;
    float bv[4];
#pragma unroll
    for (int nj = 0; nj < 4; ++nj)
        bv[nj] = bias[n0 + wc * 64 + nj * 16 + cl];

#pragma unroll
    for (int mi = 0; mi < 4; ++mi) {
#pragma unroll
        for (int i = 0; i < 4; ++i) {
            const int row = m0 + wr * 64 + mi * 16 + rg * 4 + i;  // chunk-local
            const float* erow = (MODE == 2)
                ? (embed + (size_t)seq[row] * H_SZ) : nullptr;
#pragma unroll
            for (int nj = 0; nj < 4; ++nj) {
                const int gn = n0 + wc * 64 + nj * 16 + cl;
                float v = acc[mi][nj][i] + bv[nj];
                if (MODE == 1) {
                    v = fmaxf(v, 0.f);
                    ((ushort_t*)Cp)[(size_t)row * N + gn] = f2bf(v);
                } else if (MODE == 2) {
                    ((float*)Cp)[(size_t)row * N + gn] = v + erow[gn];
                } else {
                    ((float*)Cp)[(size_t)row * N + gn] = v;
                }
            }
        }
    }
}

// ---------------------------------------------------------------------------
// LayerNorm over H=256: one wave per token, 4 tokens per block (chunk-local).
// ---------------------------------------------------------------------------
__global__ __launch_bounds__(256) void ln_k(
    const float* __restrict__ x, const float* __restrict__ g,
    const float* __restrict__ bt, ushort_t* __restrict__ h)
{
    const int token = blockIdx.x * 4 + (threadIdx.x >> 6);
    const int lane = threadIdx.x & 63;
    const float* xr = x + (size_t)token * H_SZ + lane * 4;
    const float4 v = *(const float4*)xr;
    float s = v.x + v.y + v.z + v.w;
    float sq = v.x * v.x + v.y * v.y + v.z * v.z + v.w * v.w;
#pragma unroll
    for (int m = 1; m < 64; m <<= 1) {
        s += __shfl_xor(s, m);
        sq += __shfl_xor(sq, m);
    }
    const float mu = s * (1.f / H_SZ);
    const float var = sq * (1.f / H_SZ) - mu * mu;
    const float rs = rsqrtf(var + 1e-5f);
    const int idx = lane * 4;
    const float4 gg = *(const float4*)(g + idx);
    const float4 bb = *(const float4*)(bt + idx);
    ushort_t o0 = f2bf((v.x - mu) * rs * gg.x + bb.x);
    ushort_t o1 = f2bf((v.y - mu) * rs * gg.y + bb.y);
    ushort_t o2 = f2bf((v.z - mu) * rs * gg.z + bb.z);
    ushort_t o3 = f2bf((v.w - mu) * rs * gg.w + bb.w);
    uint2 pk;
    pk.x = (uint32_t)o0 | ((uint32_t)o1 << 16);
    pk.y = (uint32_t)o2 | ((uint32_t)o3 << 16);
    *(uint2*)(h + (size_t)token * H_SZ + idx) = pk;
}

// ---------------------------------------------------------------------------
// Per-token inverse squared norms of both proj halves.
// ---------------------------------------------------------------------------
__global__ __launch_bounds__(256) void invn_k(
    const float* __restrict__ proj, float* __restrict__ invn)
{
    const int token = blockIdx.x * 4 + (threadIdx.x >> 6);
    const int lane = threadIdx.x & 63;
    const float4 v = *(const float4*)(proj + (size_t)token * H_SZ + lane * 4);
    float sq = v.x * v.x + v.y * v.y + v.z * v.z + v.w * v.w;
#pragma unroll
    for (int m = 1; m < 32; m <<= 1) sq += __shfl_xor(sq, m);
    if ((lane & 31) == 0)
        invn[(size_t)token * 2 + (lane >> 5)] = 1.0f / (sq + 1e-6f);
}

// ---------------------------------------------------------------------------
// Backward vector scan (exact algebraic transform of the matrix scan).
//   c = sum_t beta_t k_t (k_t . v_t),  v_{t-1} = v_t - alpha_t k_t (k_t . v_t)
//   v_{N-1} = q;  alpha = beta * invn;  beta = 1 (s-half) or (t+1)/L (e-half)
// One wave per (b,half) pair: 128 blocks x 64 threads, 2 elems/lane.
// W=4 lookahead: per 4 steps, 4 a-dots + 6 Gram dots reduced in ONE butterfly,
// then a scalar triangular solve; depth-2-block register prefetch.
// ---------------------------------------------------------------------------
__global__ __launch_bounds__(64) void scan_bw_k(
    const float* __restrict__ proj, const float* __restrict__ invn,
    float* __restrict__ cbuf)
{
    const int pair = blockIdx.x;        // 0..127
    const int b = pair >> 1;
    const int half = pair & 1;
    const int l = threadIdx.x;          // 0..63, owns elems 2l, 2l+1

    const float* kbase = proj + (size_t)b * L_SZ * H_SZ + half * HALF_SZ;
    const float* ibase = invn + (size_t)b * L_SZ * 2 + half;
    const float invL = 1.0f / (float)L_SZ;

    // v = q = proj row at token L-1
    float2 v = *(const float2*)(kbase + (size_t)(L_SZ - 1) * H_SZ + 2 * l);
    float2 c = make_float2(0.f, 0.f);

    // pipeline: kc = block(tb), kn = block(tb-4) in flight
    float2 kc[4], kn[4];
    float inc_[4], inn_[4];
#pragma unroll
    for (int i = 0; i < 4; ++i) {
        kc[i] = *(const float2*)(kbase + (size_t)(2046 - i) * H_SZ + 2 * l);
        inc_[i] = ibase[(size_t)(2046 - i) * 2];
        kn[i] = *(const float2*)(kbase + (size_t)(2042 - i) * H_SZ + 2 * l);
        inn_[i] = ibase[(size_t)(2042 - i) * 2];
    }

    for (int tb = 2046; tb >= 6; tb -= 4) {
        // issue prefetch for block tb-8 (clamped; garbage slots never used)
        float2 kf[4];
        float inf_[4];
#pragma unroll
        for (int i = 0; i < 4; ++i) {
            int tp = tb - 8 - i;
            tp = tp < 0 ? 0 : tp;
            kf[i] = *(const float2*)(kbase + (size_t)tp * H_SZ + 2 * l);
            inf_[i] = ibase[(size_t)tp * 2];
        }

        // 10 independent partial dots (i=0 is latest step t=tb)
        float r[10];
        r[0] = kc[0].x * v.x + kc[0].y * v.y;          // a0
        r[1] = kc[1].x * v.x + kc[1].y * v.y;          // a1
        r[2] = kc[2].x * v.x + kc[2].y * v.y;          // a2
        r[3] = kc[3].x * v.x + kc[3].y * v.y;          // a3
        r[4] = kc[0].x * kc[1].x + kc[0].y * kc[1].y;  // g01
        r[5] = kc[0].x * kc[2].x + kc[0].y * kc[2].y;  // g02
        r[6] = kc[0].x * kc[3].x + kc[0].y * kc[3].y;  // g03
        r[7] = kc[1].x * kc[2].x + kc[1].y * kc[2].y;  // g12
        r[8] = kc[1].x * kc[3].x + kc[1].y * kc[3].y;  // g13
        r[9] = kc[2].x * kc[3].x + kc[2].y * kc[3].y;  // g23

#pragma unroll
        for (int m = 1; m < 64; m <<= 1) {
#pragma unroll
            for (int j = 0; j < 10; ++j) r[j] += __shfl_xor(r[j], m);
        }

        // scalar triangular solve (uniform across wave)
        float be[4], al[4];
#pragma unroll
        for (int i = 0; i < 4; ++i) {
            be[i] = half ? (float)(tb - i + 1) * invL : 1.0f;
            al[i] = be[i] * inc_[i];
        }
        const float d0 = r[0];
        const float d1 = r[1] - al[0] * r[4] * d0;
        const float d2 = r[2] - al[0] * r[5] * d0 - al[1] * r[7] * d1;
        const float d3 = r[3] - al[0] * r[6] * d0 - al[1] * r[8] * d1
                              - al[2] * r[9] * d2;

        const float ad0 = al[0] * d0, ad1 = al[1] * d1,
                    ad2 = al[2] * d2, ad3 = al[3] * d3;
        const float bd0 = be[0] * d0, bd1 = be[1] * d1,
                    bd2 = be[2] * d2, bd3 = be[3] * d3;

        v.x -= ad0 * kc[0].x + ad1 * kc[1].x + ad2 * kc[2].x + ad3 * kc[3].x;
        v.y -= ad0 * kc[0].y + ad1 * kc[1].y + ad2 * kc[2].y + ad3 * kc[3].y;
        c.x += bd0 * kc[0].x + bd1 * kc[1].x + bd2 * kc[2].x + bd3 * kc[3].x;
        c.y += bd0 * kc[0].y + bd1 * kc[1].y + bd2 * kc[2].y + bd3 * kc[3].y;

#pragma unroll
        for (int i = 0; i < 4; ++i) {
            kc[i] = kn[i]; inc_[i] = inn_[i];
            kn[i] = kf[i]; inn_[i] = inf_[i];
        }
    }

    // peel t = 2, 1, 0 (kc[i] holds t = 2-i after the pipeline drain)
#pragma unroll
    for (int i = 0; i < 3; ++i) {
        const int t = 2 - i;
        float a = kc[i].x * v.x + kc[i].y * v.y;
#pragma unroll
        for (int m = 1; m < 64; m <<= 1) a += __shfl_xor(a, m);
        const float be = half ? (float)(t + 1) * invL : 1.0f;
        const float al = be * inc_[i];
        const float ad = al * a, bd = be * a;
        v.x -= ad * kc[i].x; v.y -= ad * kc[i].y;
        c.x += bd * kc[i].x; c.y += bd * kc[i].y;
    }

    *(float2*)(cbuf + b * H_SZ + half * HALF_SZ + 2 * l) = c;
}

// ---------------------------------------------------------------------------
// out[b, v] = sum_h c[b,h] * out_w[h,v] + out_b[v]   (f32 store)
// ---------------------------------------------------------------------------
__global__ __launch_bounds__(256) void out_k(
    const float* __restrict__ c, const float* __restrict__ w,
    const float* __restrict__ ob, float* __restrict__ out)
{
    const int b = blockIdx.x >> 2;
    const int v = ((blockIdx.x & 3) << 8) + threadIdx.x;
    const float* cb = c + b * H_SZ;
    float acc = ob[v];
#pragma unroll 4
    for (int hh = 0; hh < H_SZ; ++hh)
        acc = fmaf(cb[hh], w[(size_t)hh * V_SZ + v], acc);
    out[(size_t)b * V_SZ + v] = acc;
}

// ---------------------------------------------------------------------------
extern "C" void kernel_launch(void* const* d_in, const int* in_sizes, int n_in,
                              void* d_out, int out_size, void* d_ws, size_t ws_size,
                              hipStream_t stream)
{
    const int*   seq   = (const int*)d_in[0];
    const float* embed = (const float*)d_in[1];
    const float* w1    = (const float*)d_in[2];
    const float* b1    = (const float*)d_in[3];
    const float* w2    = (const float*)d_in[4];
    const float* b2    = (const float*)d_in[5];
    const float* ln_g  = (const float*)d_in[6];
    const float* ln_b  = (const float*)d_in[7];
    const float* kp_w  = (const float*)d_in[8];
    const float* kp_b  = (const float*)d_in[9];
    const float* out_w = (const float*)d_in[10];
    const float* out_b = (const float*)d_in[11];

    char* ws = (char*)d_ws;
    size_t off = 0;
    auto alloc = [&](size_t bytes) -> void* {
        void* p = ws + off;
        off += (bytes + 255) & ~(size_t)255;
        return p;
    };

    float*    proj = (float*)alloc((size_t)NTOK * H_SZ * sizeof(float));     // 128 MB
    ushort_t* t1_c = (ushort_t*)alloc((size_t)CH * 512 * sizeof(ushort_t));  // 16 MB
    float*    x_c  = (float*)alloc((size_t)CH * H_SZ * sizeof(float));       // 16 MB
    ushort_t* h_c  = (ushort_t*)alloc((size_t)CH * H_SZ * sizeof(ushort_t)); // 8 MB
    float*    invn = (float*)alloc((size_t)NTOK * 2 * sizeof(float));        // 1 MB
    float*    cbuf = (float*)alloc((size_t)B_SZ * H_SZ * sizeof(float));
    // bf16 weight copies
    ushort_t* embed_bf = (ushort_t*)alloc((size_t)V_SZ * H_SZ * 2);          // 512 KB
    ushort_t* w1T = (ushort_t*)alloc((size_t)512 * 256 * 2);                 // 256 KB
    ushort_t* w2T = (ushort_t*)alloc((size_t)256 * 512 * 2);                 // 256 KB
    ushort_t* kpT = (ushort_t*)alloc((size_t)256 * 256 * 2);                 // 128 KB
    float*    outp = (float*)d_out;

    const dim3 blk(256);

    // weight preconversion (bf16 / transposed-bf16)
    cvt_bf16_k<<<dim3((V_SZ * H_SZ) / 1024), blk, 0, stream>>>(
        embed, embed_bf, V_SZ * H_SZ);
    transpose_cvt_k<<<dim3((256 * 512) / 256), blk, 0, stream>>>(w1, w1T, 256, 512);
    transpose_cvt_k<<<dim3((512 * 256) / 256), blk, 0, stream>>>(w2, w2T, 512, 256);
    transpose_cvt_k<<<dim3((256 * 256) / 256), blk, 0, stream>>>(kp_w, kpT, 256, 256);

    for (int c = 0; c < NTOK / CH; ++c) {
        const int base = c * CH;
        const int* seq_c = seq + base;
        // GEMM1: t1 = relu(embed[seq] @ w1 + b1)     M=CH K=256 N=512
        gemm_mfma<1, 256, 512><<<dim3(CH / 128, 4), blk, 0, stream>>>(
            embed_bf, w1T, b1, t1_c, seq_c, nullptr);
        // GEMM2: x = t1 @ w2 + b2 + embed[seq]       M=CH K=512 N=256
        gemm_mfma<2, 512, 256><<<dim3(CH / 128, 2), blk, 0, stream>>>(
            t1_c, w2T, b2, x_c, seq_c, embed);
        // LN: h = LN(x) * g + b  (bf16)
        ln_k<<<dim3(CH / 4), blk, 0, stream>>>(x_c, ln_g, ln_b, h_c);
        // GEMM3: proj = h @ kp_w + kp_b              M=CH K=256 N=256
        gemm_mfma<3, 256, 256><<<dim3(CH / 128, 2), blk, 0, stream>>>(
            h_c, kpT, kp_b, proj + (size_t)base * H_SZ, seq_c, nullptr);
    }

    invn_k<<<dim3(NTOK / 4), blk, 0, stream>>>(proj, invn);
    // backward vector scan: c = M_final q without materializing M
    scan_bw_k<<<dim3(128), dim3(64), 0, stream>>>(proj, invn, cbuf);
    out_k<<<dim3(B_SZ * 4), blk, 0, stream>>>(cbuf, out_w, out_b, outp);
}